// Round 16
// baseline (213.693 us; speedup 1.0000x reference)
//
#include <hip/hip_runtime.h>

typedef unsigned short u16;
typedef short bf16x8 __attribute__((ext_vector_type(8)));
typedef u16 u16x8 __attribute__((ext_vector_type(8)));
typedef float f32x4 __attribute__((ext_vector_type(4)));

#define K_DIM 256
#define L_DIM 4096
#define NBATCH 4

static __device__ __forceinline__ u16 f2bf(float f) {
    unsigned u = __float_as_uint(f);
    unsigned r = (u + 0x7FFFu + ((u >> 16) & 1u)) >> 16;
    return (u16)r;
}
static __device__ __forceinline__ float bf2f(u16 v) {
    return __uint_as_float(((unsigned)v) << 16);
}

#define GLOAD16(g, l) __builtin_amdgcn_global_load_lds( \
    (const __attribute__((address_space(1))) void*)(g), \
    (__attribute__((address_space(3))) void*)(l), 16, 0, 0)

// ---------------------------------------------------------------------------
// K1: depthwise 3x3 conv + transpose + bf16 cast; weight casts folded in.
// [R15 verbatim]
// ---------------------------------------------------------------------------
__global__ __launch_bounds__(256) void prep_kernel(
    const float* __restrict__ x, const float* __restrict__ dw_w,
    const float* __restrict__ dw_b, const float* __restrict__ pin_w,
    const float* __restrict__ pw_w, const float* __restrict__ pout_w,
    u16* __restrict__ xb_t, u16* __restrict__ dwc_t,
    u16* __restrict__ pin_wb, u16* __restrict__ pw_wb,
    u16* __restrict__ pout_wb)
{
    if (blockIdx.x == 4) {                      // weight-cast blocks
        if (blockIdx.z != 0) return;
        const int end = (blockIdx.y + 1) * 2560;
        for (int k = blockIdx.y * 2560 + threadIdx.x; k < end; k += 256) {
            if (k < 65536) pin_wb[k] = f2bf(pin_w[k]);
            else if (k < 98304) {
                int j = k - 65536;
                pw_wb[j] = ((j >> 8) < 112) ? f2bf(pw_w[j]) : (u16)0;
            } else {
                int j = k - 98304;
                pout_wb[j] = f2bf(pout_w[j]);
            }
        }
        return;
    }

    __shared__ u16 tx_[64][66];
    __shared__ u16 td_[64][66];
    const int c0 = blockIdx.x * 64, h = blockIdx.y, n = blockIdx.z;
    const int t = threadIdx.x;
    const float* xn = x + (size_t)n * 256 * L_DIM;

    const int w4 = (t & 15) * 4;          // 0..60
    const int cs = t >> 4;                // 0..15

    #pragma unroll
    for (int j = 0; j < 4; ++j) {
        const int cl = cs * 4 + j, c = c0 + cl;
        const float* xc = xn + (size_t)c * L_DIM;
        const float* w9 = dw_w + c * 9;

        float s[4];
        const float bv = dw_b[c];
        #pragma unroll
        for (int k = 0; k < 4; ++k) s[k] = bv;
        f32x4 center;

        #pragma unroll
        for (int dy = 0; dy < 3; ++dy) {
            const int hh = h + dy - 1;
            if (hh < 0 || hh > 63) continue;        // block-uniform
            const float* row = xc + hh * 64;
            const f32x4 m = *(const f32x4*)(row + w4);
            const float flv = row[(w4 > 0) ? w4 - 1 : 0];
            const float frv = row[(w4 + 4 < 64) ? w4 + 4 : 63];
            if (dy == 1) center = m;
            #pragma unroll
            for (int k = 0; k < 4; ++k) {
                const int w = w4 + k;
                const float lv = (w > 0) ? 1.f : 0.f;
                const float rv = (w < 63) ? 1.f : 0.f;
                const float xm = (k == 0) ? flv : m[k - 1];
                const float xp = (k == 3) ? frv : m[k + 1];
                s[k] = fmaf(xm * lv, w9[dy*3 + 0], s[k]);
                s[k] = fmaf(m[k],    w9[dy*3 + 1], s[k]);
                s[k] = fmaf(xp * rv, w9[dy*3 + 2], s[k]);
            }
        }
        #pragma unroll
        for (int k = 0; k < 4; ++k) {
            tx_[w4 + k][cl] = f2bf(center[k]);
            td_[w4 + k][cl] = f2bf(s[k]);
        }
    }
    __syncthreads();

    const int cc = t & 63, cq = t >> 6;
    for (int j = 0; j < 16; ++j) {
        const int wl = j * 4 + cq;
        const size_t o = ((size_t)n * L_DIM + h * 64 + wl) * 256 + c0 + cc;
        xb_t[o]  = tx_[wl][cc];
        dwc_t[o] = td_[wl][cc];
    }
}

// ---------------------------------------------------------------------------
// K2: pin + pw GEMMs in one dispatch.   [R15 verbatim]
// ---------------------------------------------------------------------------
__global__ __launch_bounds__(256) void gemm_dual(
    const u16* __restrict__ xb_t, const u16* __restrict__ dwc_t,
    const u16* __restrict__ pin_wb, const u16* __restrict__ pw_wb,
    const float* __restrict__ pin_b, const float* __restrict__ pw_b,
    u16* __restrict__ val_b, float* __restrict__ omb)
{
    __shared__ u16 lds[16384];
    const int bx = blockIdx.x;
    const bool isPw = (bx == 2);
    const u16* Ag = isPw ? dwc_t : xb_t;
    const u16* Bg = isPw ? pw_wb : pin_wb;
    const float* bias = isPw ? pw_b : pin_b;
    const int n0 = isPw ? 0 : bx * 128;
    const int Ncols = isPw ? 112 : 256;
    const int ldC = isPw ? 112 : 256;
    const int m0 = blockIdx.y * 128;

    const int t = threadIdx.x;
    const int wave = t >> 6, lane = t & 63;
    const int lr = lane & 15, lk = lane >> 4;
    const int wr = wave >> 1, wc = wave & 1;
    const int wbase = wave << 10;

    const int srow = t >> 2;
    const int scol = (t & 3) * 8;
    const u16* ga0 = Ag + (size_t)(m0 + srow)      * K_DIM + scol;
    const u16* ga1 = Ag + (size_t)(m0 + 64 + srow) * K_DIM + scol;
    const u16* gb0 = Bg + (size_t)(n0 + srow)      * K_DIM + scol;
    const u16* gb1 = Bg + (size_t)(n0 + 64 + srow) * K_DIM + scol;

    f32x4 acc[4][4];
    #pragma unroll
    for (int m = 0; m < 4; ++m)
        #pragma unroll
        for (int n = 0; n < 4; ++n) acc[m][n] = (f32x4){0.f, 0.f, 0.f, 0.f};

    auto stage = [&](int b, int kt) {
        const int ko = kt * 32;
        char* base = (char*)lds + b * 16384 + wbase;
        GLOAD16(ga0 + ko, base);
        GLOAD16(ga1 + ko, base + 4096);
        GLOAD16(gb0 + ko, base + 8192);
        GLOAD16(gb1 + ko, base + 12288);
    };

    stage(0, 0);
    asm volatile("s_waitcnt vmcnt(0)" ::: "memory");
    __syncthreads();

    for (int kt = 0; kt < 8; ++kt) {
        const int cur = kt & 1;
        if (kt < 7) stage(cur ^ 1, kt + 1);
        const char* la = (const char*)lds + cur * 16384;
        const char* lb = la + 8192;
        bf16x8 af[4], bfr[4];
        #pragma unroll
        for (int m = 0; m < 4; ++m)
            af[m] = *(const bf16x8*)(la + ((wr*64 + m*16 + lr) * 32 + lk * 8) * 2);
        #pragma unroll
        for (int n = 0; n < 4; ++n)
            bfr[n] = *(const bf16x8*)(lb + ((wc*64 + n*16 + lr) * 32 + lk * 8) * 2);
        #pragma unroll
        for (int m = 0; m < 4; ++m)
            #pragma unroll
            for (int n = 0; n < 4; ++n)
                acc[m][n] = __builtin_amdgcn_mfma_f32_16x16x32_bf16(
                    af[m], bfr[n], acc[m][n], 0, 0, 0);
        asm volatile("s_waitcnt vmcnt(0)" ::: "memory");
        __syncthreads();
    }

    #pragma unroll
    for (int m = 0; m < 4; ++m) {
        #pragma unroll
        for (int n = 0; n < 4; ++n) {
            const int col = n0 + wc*64 + n*16 + lr;
            if (col < Ncols) {
                const float bv = bias[col];
                #pragma unroll
                for (int r = 0; r < 4; ++r) {
                    const int row = m0 + wr*64 + m*16 + lk*4 + r;
                    const float o = acc[m][n][r] + bv;
                    const size_t off = (size_t)row * ldC + col;
                    if (isPw) omb[off] = o;
                    else      val_b[off] = f2bf(o);
                }
            }
        }
    }
}

// ---------------------------------------------------------------------------
// K3a: deformable bilinear gather — async global_load_lds pipeline.
// Corner loads become fire-and-forget DMA into per-thread LDS slots
// (stage[buf][corner][t*8], linear in t per wave); depth controlled by
// COUNTED vmcnt(4) (never 0 mid-loop).  Each thread reads back only its own
// 16B slot -> no barriers, only vmcnt/lgkmcnt.  Weights recomputed at
// consume time from som (identical exprs -> bitwise-identical; no
// cross-iteration register state -> no R13-style scratch spill).
// FMA order (p asc, corner asc) unchanged -> bitwise-identical output.
// ---------------------------------------------------------------------------
__global__ __launch_bounds__(256, 4) void gather_kernel(
    const float* __restrict__ om, const u16* __restrict__ val,
    u16* __restrict__ accb)
{
    __shared__ float som[904];                  // 3.6 KB
    __shared__ u16 stage[2][4][2048];           // 32 KB: [tapbuf][corner][t*8]
    const int blk = blockIdx.x;                 // 0..2047
    const int grp = (blk & 7) * 256 + (blk >> 3);
    const int n = grp >> 9;
    const int l0 = (grp & 511) * 8;
    const int t = threadIdx.x;

    // stage om slice (3584 B)
    {
        const float* omsrc = om + ((size_t)n * L_DIM + l0) * 112;
        if (t < 224) {
            const int wb = (t >> 6) << 10;
            GLOAD16(omsrc + t * 4, (char*)som + wb);
        }
        asm volatile("s_waitcnt vmcnt(0)" ::: "memory");
        __syncthreads();
    }

    const int pos = t >> 5;
    const int g = (t >> 3) & 3;
    const int ch = (t & 7) * 8;
    const int l = l0 + pos;
    const float* omp = som + pos * 112 + g * 27;
    const u16* vb = val + (size_t)n * L_DIM * 256 + g * 64 + ch;
    const float ybase = (float)(l >> 6) - 1.f;
    const float xb = (float)(l & 63) - 1.f;

    // issue tap p's 4 corner DMAs into buffer `buf` (addresses only)
    auto ISSUE = [&](int p, int buf) {
        const float oy = omp[p*3 + 1];
        const float ox = omp[p*3 + 0];
        const float py = ybase + (float)(p / 3) + oy;
        const float px = xb + (float)(p % 3) + ox;
        const int iy0 = (int)floorf(py);
        const int ix0 = (int)floorf(px);
        #pragma unroll
        for (int c4 = 0; c4 < 4; ++c4) {
            const int iy = iy0 + (c4 >> 1), ix = ix0 + (c4 & 1);
            const int iyc = min(max(iy, 0), 63);
            const int ixc = min(max(ix, 0), 63);
            GLOAD16(vb + (size_t)(iyc * 64 + ixc) * 256, &stage[buf][c4][t * 8]);
        }
    };

    float a[8];
    #pragma unroll
    for (int j = 0; j < 8; ++j) a[j] = 0.f;

    ISSUE(0, 0);
    ISSUE(1, 1);

    #pragma unroll
    for (int p = 0; p < 9; ++p) {
        const int buf = p & 1;
        // tap p's DMAs landed (taps p..p+1 outstanding = 8 instrs -> keep 4)
        if (p < 8) { asm volatile("s_waitcnt vmcnt(4)" ::: "memory"); }
        else       { asm volatile("s_waitcnt vmcnt(0)" ::: "memory"); }
        // read back own slots
        const u16x8 v0 = *(const u16x8*)&stage[buf][0][t * 8];
        const u16x8 v1 = *(const u16x8*)&stage[buf][1][t * 8];
        const u16x8 v2 = *(const u16x8*)&stage[buf][2][t * 8];
        const u16x8 v3 = *(const u16x8*)&stage[buf][3][t * 8];
        // pin reads complete before this buffer is re-targeted by DMA
        asm volatile("s_waitcnt lgkmcnt(0)" ::: "memory");
        if (p < 7) ISSUE(p + 2, buf);
        // recompute weights (identical expressions -> identical values)
        const float oy = omp[p*3 + 1];
        const float ox = omp[p*3 + 0];
        const float mk = omp[p*3 + 2];
        const float py = ybase + (float)(p / 3) + oy;
        const float px = xb + (float)(p % 3) + ox;
        const float y0 = floorf(py), x0 = floorf(px);
        const float fy = py - y0, fx = px - x0;
        const int iy0 = (int)y0, ix0 = (int)x0;
        const float wy[2] = {mk * (1.f - fy), mk * fy};
        const float wx[2] = {1.f - fx, fx};
        float wgt[4];
        #pragma unroll
        for (int c4 = 0; c4 < 4; ++c4) {
            const int iy = iy0 + (c4 >> 1), ix = ix0 + (c4 & 1);
            const bool ok = ((unsigned)iy < 64u) & ((unsigned)ix < 64u);
            wgt[c4] = ok ? wy[c4 >> 1] * wx[c4 & 1] : 0.f;
        }
        #pragma unroll
        for (int j = 0; j < 8; ++j) a[j] = fmaf(wgt[0], bf2f(v0[j]), a[j]);
        #pragma unroll
        for (int j = 0; j < 8; ++j) a[j] = fmaf(wgt[1], bf2f(v1[j]), a[j]);
        #pragma unroll
        for (int j = 0; j < 8; ++j) a[j] = fmaf(wgt[2], bf2f(v2[j]), a[j]);
        #pragma unroll
        for (int j = 0; j < 8; ++j) a[j] = fmaf(wgt[3], bf2f(v3[j]), a[j]);
    }

    u16x8 o;
    #pragma unroll
    for (int j = 0; j < 8; ++j) o[j] = f2bf(a[j]);
    *(u16x8*)(accb + ((size_t)n * L_DIM + l) * 256 + g * 64 + ch) = o;
}

// ---------------------------------------------------------------------------
// K3b: pout GEMM.  [R15 verbatim]
// ---------------------------------------------------------------------------
__global__ __launch_bounds__(256) void gemm_pout(
    const u16* __restrict__ accb, const u16* __restrict__ pout_wb,
    const float* __restrict__ pout_b, float* __restrict__ out)
{
    __shared__ u16 lds[16384];
    const int z = blockIdx.z;
    const u16* Bg = accb + (size_t)z * L_DIM * 256;
    const int n0 = blockIdx.x * 128;           // l tile
    const int m0 = blockIdx.y * 128;           // c tile

    const int t = threadIdx.x;
    const int wave = t >> 6, lane = t & 63;
    const int lr = lane & 15, lk = lane >> 4;
    const int wr = wave >> 1, wc = wave & 1;
    const int wbase = wave << 10;

    const int srow = t >> 2;
    const int scol = (t & 3) * 8;
    const u16* ga0 = pout_wb + (size_t)(m0 + srow)      * K_DIM + scol;
    const u16* ga1 = pout_wb + (size_t)(m0 + 64 + srow) * K_DIM + scol;
    const u16* gb0 = Bg + (size_t)(n0 + srow)      * K_DIM + scol;
    const u16* gb1 = Bg + (size_t)(n0 + 64 + srow) * K_DIM + scol;

    f32x4 acc[4][4];
    #pragma unroll
    for (int m = 0; m < 4; ++m)
        #pragma unroll
        for (int n = 0; n < 4; ++n) acc[m][n] = (f32x4){0.f, 0.f, 0.f, 0.f};

    auto stage = [&](int b, int kt) {
        const int ko = kt * 32;
        char* base = (char*)lds + b * 16384 + wbase;
        GLOAD16(ga0 + ko, base);
        GLOAD16(ga1 + ko, base + 4096);
        GLOAD16(gb0 + ko, base + 8192);
        GLOAD16(gb1 + ko, base + 12288);
    };

    stage(0, 0);
    asm volatile("s_waitcnt vmcnt(0)" ::: "memory");
    __syncthreads();

    for (int kt = 0; kt < 8; ++kt) {
        const int cur = kt & 1;
        if (kt < 7) stage(cur ^ 1, kt + 1);
        const char* la = (const char*)lds + cur * 16384;
        const char* lb = la + 8192;
        bf16x8 af[4], bfr[4];
        #pragma unroll
        for (int m = 0; m < 4; ++m)
            af[m] = *(const bf16x8*)(la + ((wr*64 + m*16 + lr) * 32 + lk * 8) * 2);
        #pragma unroll
        for (int n = 0; n < 4; ++n)
            bfr[n] = *(const bf16x8*)(lb + ((wc*64 + n*16 + lr) * 32 + lk * 8) * 2);
        #pragma unroll
        for (int m = 0; m < 4; ++m)
            #pragma unroll
            for (int n = 0; n < 4; ++n)
                acc[m][n] = __builtin_amdgcn_mfma_f32_16x16x32_bf16(
                    af[m], bfr[n], acc[m][n], 0, 0, 0);
        asm volatile("s_waitcnt vmcnt(0)" ::: "memory");
        __syncthreads();
    }

    float* outn = out + (size_t)z * 256 * L_DIM;
    #pragma unroll
    for (int m = 0; m < 4; ++m) {
        #pragma unroll
        for (int n = 0; n < 4; ++n) {
            const int col = n0 + wc*64 + n*16 + lr;
            #pragma unroll
            for (int r = 0; r < 4; ++r) {
                const int row = m0 + wr*64 + m*16 + lk*4 + r;
                outn[(size_t)row * L_DIM + col] = acc[m][n][r] + pout_b[row];
            }
        }
    }
}

// ---------------------------------------------------------------------------
extern "C" void kernel_launch(void* const* d_in, const int* in_sizes, int n_in,
                              void* d_out, int out_size, void* d_ws, size_t ws_size,
                              hipStream_t stream) {
    const float* x      = (const float*)d_in[0];
    const float* dw_w   = (const float*)d_in[1];
    const float* dw_b   = (const float*)d_in[2];
    const float* pw_w   = (const float*)d_in[3];
    const float* pw_b   = (const float*)d_in[4];
    const float* pin_w  = (const float*)d_in[5];
    const float* pin_b  = (const float*)d_in[6];
    const float* pout_w = (const float*)d_in[7];
    const float* pout_b = (const float*)d_in[8];
    float* out = (float*)d_out;

    char* ws = (char*)d_ws;
    u16*   xb_t    = (u16*)ws;                      //  8,388,608
    u16*   dwc_t   = (u16*)(ws + 8388608);          //  8,388,608
    u16*   val_b   = (u16*)(ws + 16777216);         //  8,388,608
    u16*   acc_b   = (u16*)(ws + 25165824);         //  8,388,608
    float* omb     = (float*)(ws + 33554432);       //  7,340,032
    u16*   pin_wb  = (u16*)(ws + 40894464);         //    131,072
    u16*   pw_wb   = (u16*)(ws + 41025536);         //     65,536 (128 rows)
    u16*   pout_wb = (u16*)(ws + 41091072);         //    131,072

    // K1: depthwise conv + transpose-cast + weight casts
    prep_kernel<<<dim3(5, 64, NBATCH), 256, 0, stream>>>(
        x, dw_w, dw_b, pin_w, pw_w, pout_w,
        xb_t, dwc_t, pin_wb, pw_wb, pout_wb);

    // K2: val = pin(x) [bf16], om = pw(dwc) [fp32]
    gemm_dual<<<dim3(3, 128), 256, 0, stream>>>(
        xb_t, dwc_t, pin_wb, pw_wb, pin_b, pw_b, val_b, omb);

    // K3a: deformable gather via async global_load_lds pipeline
    gather_kernel<<<dim3(2048), 256, 0, stream>>>(omb, val_b, acc_b);

    // K3b: pout GEMM, transposed fp32 output
    gemm_pout<<<dim3(32, 2, NBATCH), 256, 0, stream>>>(
        acc_b, pout_wb, pout_b, out);
}

// Round 17
// 55.382 us; speedup vs baseline: 3.8585x; 3.8585x over previous
//
#include <hip/hip_runtime.h>

typedef unsigned short u16;
typedef short bf16x8 __attribute__((ext_vector_type(8)));
typedef u16 u16x8 __attribute__((ext_vector_type(8)));
typedef float f32x4 __attribute__((ext_vector_type(4)));

#define K_DIM 256
#define L_DIM 4096
#define NBATCH 4

static __device__ __forceinline__ u16 f2bf(float f) {
    unsigned u = __float_as_uint(f);
    unsigned r = (u + 0x7FFFu + ((u >> 16) & 1u)) >> 16;
    return (u16)r;
}
static __device__ __forceinline__ float bf2f(u16 v) {
    return __uint_as_float(((unsigned)v) << 16);
}

#define GLOAD16(g, l) __builtin_amdgcn_global_load_lds( \
    (const __attribute__((address_space(1))) void*)(g), \
    (__attribute__((address_space(3))) void*)(l), 16, 0, 0)

// ---------------------------------------------------------------------------
// K1: depthwise 3x3 conv + transpose + bf16 cast; weight casts folded in.
// [R15 verbatim]
// ---------------------------------------------------------------------------
__global__ __launch_bounds__(256) void prep_kernel(
    const float* __restrict__ x, const float* __restrict__ dw_w,
    const float* __restrict__ dw_b, const float* __restrict__ pin_w,
    const float* __restrict__ pw_w, const float* __restrict__ pout_w,
    u16* __restrict__ xb_t, u16* __restrict__ dwc_t,
    u16* __restrict__ pin_wb, u16* __restrict__ pw_wb,
    u16* __restrict__ pout_wb)
{
    if (blockIdx.x == 4) {                      // weight-cast blocks
        if (blockIdx.z != 0) return;
        const int end = (blockIdx.y + 1) * 2560;
        for (int k = blockIdx.y * 2560 + threadIdx.x; k < end; k += 256) {
            if (k < 65536) pin_wb[k] = f2bf(pin_w[k]);
            else if (k < 98304) {
                int j = k - 65536;
                pw_wb[j] = ((j >> 8) < 112) ? f2bf(pw_w[j]) : (u16)0;
            } else {
                int j = k - 98304;
                pout_wb[j] = f2bf(pout_w[j]);
            }
        }
        return;
    }

    __shared__ u16 tx_[64][66];
    __shared__ u16 td_[64][66];
    const int c0 = blockIdx.x * 64, h = blockIdx.y, n = blockIdx.z;
    const int t = threadIdx.x;
    const float* xn = x + (size_t)n * 256 * L_DIM;

    const int w4 = (t & 15) * 4;          // 0..60
    const int cs = t >> 4;                // 0..15

    #pragma unroll
    for (int j = 0; j < 4; ++j) {
        const int cl = cs * 4 + j, c = c0 + cl;
        const float* xc = xn + (size_t)c * L_DIM;
        const float* w9 = dw_w + c * 9;

        float s[4];
        const float bv = dw_b[c];
        #pragma unroll
        for (int k = 0; k < 4; ++k) s[k] = bv;
        f32x4 center;

        #pragma unroll
        for (int dy = 0; dy < 3; ++dy) {
            const int hh = h + dy - 1;
            if (hh < 0 || hh > 63) continue;        // block-uniform
            const float* row = xc + hh * 64;
            const f32x4 m = *(const f32x4*)(row + w4);
            const float flv = row[(w4 > 0) ? w4 - 1 : 0];
            const float frv = row[(w4 + 4 < 64) ? w4 + 4 : 63];
            if (dy == 1) center = m;
            #pragma unroll
            for (int k = 0; k < 4; ++k) {
                const int w = w4 + k;
                const float lv = (w > 0) ? 1.f : 0.f;
                const float rv = (w < 63) ? 1.f : 0.f;
                const float xm = (k == 0) ? flv : m[k - 1];
                const float xp = (k == 3) ? frv : m[k + 1];
                s[k] = fmaf(xm * lv, w9[dy*3 + 0], s[k]);
                s[k] = fmaf(m[k],    w9[dy*3 + 1], s[k]);
                s[k] = fmaf(xp * rv, w9[dy*3 + 2], s[k]);
            }
        }
        #pragma unroll
        for (int k = 0; k < 4; ++k) {
            tx_[w4 + k][cl] = f2bf(center[k]);
            td_[w4 + k][cl] = f2bf(s[k]);
        }
    }
    __syncthreads();

    const int cc = t & 63, cq = t >> 6;
    for (int j = 0; j < 16; ++j) {
        const int wl = j * 4 + cq;
        const size_t o = ((size_t)n * L_DIM + h * 64 + wl) * 256 + c0 + cc;
        xb_t[o]  = tx_[wl][cc];
        dwc_t[o] = td_[wl][cc];
    }
}

// ---------------------------------------------------------------------------
// K2: pin + pw GEMMs in one dispatch.
// CHANGE vs R15: tile 128x128 -> 64x128 (M halved).  Grid (3, 256) = 768
// blocks = 3 blocks/CU (was 1.5) for better latency hiding.  LDS 24 KB,
// 3 GLOAD16/thread/K-step.  Same MFMA kt order -> bitwise-identical output.
// Wave w owns all 64 m-rows x n-cols [w*32, w*32+32).
// ---------------------------------------------------------------------------
__global__ __launch_bounds__(256) void gemm_dual(
    const u16* __restrict__ xb_t, const u16* __restrict__ dwc_t,
    const u16* __restrict__ pin_wb, const u16* __restrict__ pw_wb,
    const float* __restrict__ pin_b, const float* __restrict__ pw_b,
    u16* __restrict__ val_b, float* __restrict__ omb)
{
    __shared__ u16 lds[12288];                 // 2 buf x (A 4KB | B 8KB)
    const int bx = blockIdx.x;
    const bool isPw = (bx == 2);
    const u16* Ag = isPw ? dwc_t : xb_t;
    const u16* Bg = isPw ? pw_wb : pin_wb;
    const float* bias = isPw ? pw_b : pin_b;
    const int n0 = isPw ? 0 : bx * 128;
    const int Ncols = isPw ? 112 : 256;
    const int ldC = isPw ? 112 : 256;
    const int m0 = blockIdx.y * 64;

    const int t = threadIdx.x;
    const int wave = t >> 6, lane = t & 63;
    const int lr = lane & 15, lk = lane >> 4;
    const int wbase = wave << 10;

    const int srow = t >> 2;                   // 0..63
    const int scol = (t & 3) * 8;
    const u16* ga  = Ag + (size_t)(m0 + srow)      * K_DIM + scol;
    const u16* gb0 = Bg + (size_t)(n0 + srow)      * K_DIM + scol;
    const u16* gb1 = Bg + (size_t)(n0 + 64 + srow) * K_DIM + scol;

    f32x4 acc[4][2];
    #pragma unroll
    for (int m = 0; m < 4; ++m)
        #pragma unroll
        for (int nn = 0; nn < 2; ++nn) acc[m][nn] = (f32x4){0.f, 0.f, 0.f, 0.f};

    auto stage = [&](int b, int kt) {
        const int ko = kt * 32;
        char* base = (char*)lds + b * 12288 + wbase;
        GLOAD16(ga + ko,  base);               // A region (4 KB)
        GLOAD16(gb0 + ko, base + 4096);        // B rows 0-63
        GLOAD16(gb1 + ko, base + 8192);        // B rows 64-127
    };

    stage(0, 0);
    asm volatile("s_waitcnt vmcnt(0)" ::: "memory");
    __syncthreads();

    for (int kt = 0; kt < 8; ++kt) {
        const int cur = kt & 1;
        if (kt < 7) stage(cur ^ 1, kt + 1);
        const char* la = (const char*)lds + cur * 12288;
        const char* lb = la + 4096;
        bf16x8 af[4], bfr[2];
        #pragma unroll
        for (int m = 0; m < 4; ++m)
            af[m] = *(const bf16x8*)(la + ((m*16 + lr) * 32 + lk * 8) * 2);
        #pragma unroll
        for (int nn = 0; nn < 2; ++nn)
            bfr[nn] = *(const bf16x8*)(lb + ((wave*32 + nn*16 + lr) * 32 + lk * 8) * 2);
        #pragma unroll
        for (int m = 0; m < 4; ++m)
            #pragma unroll
            for (int nn = 0; nn < 2; ++nn)
                acc[m][nn] = __builtin_amdgcn_mfma_f32_16x16x32_bf16(
                    af[m], bfr[nn], acc[m][nn], 0, 0, 0);
        asm volatile("s_waitcnt vmcnt(0)" ::: "memory");
        __syncthreads();
    }

    #pragma unroll
    for (int m = 0; m < 4; ++m) {
        #pragma unroll
        for (int nn = 0; nn < 2; ++nn) {
            const int col = n0 + wave*32 + nn*16 + lr;
            if (col < Ncols) {
                const float bv = bias[col];
                #pragma unroll
                for (int r = 0; r < 4; ++r) {
                    const int row = m0 + m*16 + lk*4 + r;
                    const float o = acc[m][nn][r] + bv;
                    const size_t off = (size_t)row * ldC + col;
                    if (isPw) omb[off] = o;
                    else      val_b[off] = f2bf(o);
                }
            }
        }
    }
}

// ---------------------------------------------------------------------------
// K3a: deformable bilinear gather.  [R15 verbatim — best measured config]
// ---------------------------------------------------------------------------
__global__ __launch_bounds__(256, 4) void gather_kernel(
    const float* __restrict__ om, const u16* __restrict__ val,
    u16* __restrict__ accb)
{
    __shared__ float som[904];                 // 8*112 floats + pad
    const int blk = blockIdx.x;                // 0..2047
    const int grp = (blk & 7) * 256 + (blk >> 3);   // pos-group 0..2047
    const int n = grp >> 9;                    // 512 groups per n
    const int l0 = (grp & 511) * 8;            // 8-pos base within n
    const int t = threadIdx.x;

    // stage om slice (3584 B): waves 0-2 full, wave 3 lanes 0-31
    {
        const float* omsrc = om + ((size_t)n * L_DIM + l0) * 112;
        if (t < 224) {
            const int wb = (t >> 6) << 10;     // wave-uniform byte base
            GLOAD16(omsrc + t * 4, (char*)som + wb);
        }
        asm volatile("s_waitcnt vmcnt(0)" ::: "memory");
        __syncthreads();
    }

    const int pos = t >> 5;                    // 0..7
    const int g = (t >> 3) & 3;
    const int ch = (t & 7) * 8;
    const int l = l0 + pos;
    const float* omp = som + pos * 112 + g * 27;
    const u16* vb = val + (size_t)n * L_DIM * 256 + g * 64 + ch;
    const float ybase = (float)(l >> 6) - 1.f;
    const float xb = (float)(l & 63) - 1.f;

    float a[8];
    #pragma unroll
    for (int j = 0; j < 8; ++j) a[j] = 0.f;

    #pragma unroll
    for (int p = 0; p < 9; ++p) {
        const float ox = omp[p*3 + 0];
        const float oy = omp[p*3 + 1];
        const float mk = omp[p*3 + 2];
        const float py = ybase + (float)(p / 3) + oy;
        const float px = xb + (float)(p % 3) + ox;
        const float y0 = floorf(py), x0 = floorf(px);
        const float fy = py - y0, fx = px - x0;
        const int iy0 = (int)y0, ix0 = (int)x0;
        const float wy[2] = {mk * (1.f - fy), mk * fy};
        const float wx[2] = {1.f - fx, fx};
        #pragma unroll
        for (int c4 = 0; c4 < 4; ++c4) {
            const int dy = c4 >> 1, dx = c4 & 1;
            const int iy = iy0 + dy, ix = ix0 + dx;
            const bool ok = ((unsigned)iy < 64u) & ((unsigned)ix < 64u);
            const float wgt = ok ? wy[dy] * wx[dx] : 0.f;
            const int iyc = min(max(iy, 0), 63);
            const int ixc = min(max(ix, 0), 63);
            const u16x8 v = *(const u16x8*)(vb + (size_t)(iyc * 64 + ixc) * 256);
            #pragma unroll
            for (int j = 0; j < 8; ++j) a[j] = fmaf(wgt, bf2f(v[j]), a[j]);
        }
    }
    u16x8 o;
    #pragma unroll
    for (int j = 0; j < 8; ++j) o[j] = f2bf(a[j]);
    *(u16x8*)(accb + ((size_t)n * L_DIM + l) * 256 + g * 64 + ch) = o;
}

// ---------------------------------------------------------------------------
// K3b: pout GEMM.  [R15 verbatim]
// ---------------------------------------------------------------------------
__global__ __launch_bounds__(256) void gemm_pout(
    const u16* __restrict__ accb, const u16* __restrict__ pout_wb,
    const float* __restrict__ pout_b, float* __restrict__ out)
{
    __shared__ u16 lds[16384];
    const int z = blockIdx.z;
    const u16* Bg = accb + (size_t)z * L_DIM * 256;
    const int n0 = blockIdx.x * 128;           // l tile
    const int m0 = blockIdx.y * 128;           // c tile

    const int t = threadIdx.x;
    const int wave = t >> 6, lane = t & 63;
    const int lr = lane & 15, lk = lane >> 4;
    const int wr = wave >> 1, wc = wave & 1;
    const int wbase = wave << 10;

    const int srow = t >> 2;
    const int scol = (t & 3) * 8;
    const u16* ga0 = pout_wb + (size_t)(m0 + srow)      * K_DIM + scol;
    const u16* ga1 = pout_wb + (size_t)(m0 + 64 + srow) * K_DIM + scol;
    const u16* gb0 = Bg + (size_t)(n0 + srow)      * K_DIM + scol;
    const u16* gb1 = Bg + (size_t)(n0 + 64 + srow) * K_DIM + scol;

    f32x4 acc[4][4];
    #pragma unroll
    for (int m = 0; m < 4; ++m)
        #pragma unroll
        for (int n = 0; n < 4; ++n) acc[m][n] = (f32x4){0.f, 0.f, 0.f, 0.f};

    auto stage = [&](int b, int kt) {
        const int ko = kt * 32;
        char* base = (char*)lds + b * 16384 + wbase;
        GLOAD16(ga0 + ko, base);
        GLOAD16(ga1 + ko, base + 4096);
        GLOAD16(gb0 + ko, base + 8192);
        GLOAD16(gb1 + ko, base + 12288);
    };

    stage(0, 0);
    asm volatile("s_waitcnt vmcnt(0)" ::: "memory");
    __syncthreads();

    for (int kt = 0; kt < 8; ++kt) {
        const int cur = kt & 1;
        if (kt < 7) stage(cur ^ 1, kt + 1);
        const char* la = (const char*)lds + cur * 16384;
        const char* lb = la + 8192;
        bf16x8 af[4], bfr[4];
        #pragma unroll
        for (int m = 0; m < 4; ++m)
            af[m] = *(const bf16x8*)(la + ((wr*64 + m*16 + lr) * 32 + lk * 8) * 2);
        #pragma unroll
        for (int n = 0; n < 4; ++n)
            bfr[n] = *(const bf16x8*)(lb + ((wc*64 + n*16 + lr) * 32 + lk * 8) * 2);
        #pragma unroll
        for (int m = 0; m < 4; ++m)
            #pragma unroll
            for (int n = 0; n < 4; ++n)
                acc[m][n] = __builtin_amdgcn_mfma_f32_16x16x32_bf16(
                    af[m], bfr[n], acc[m][n], 0, 0, 0);
        asm volatile("s_waitcnt vmcnt(0)" ::: "memory");
        __syncthreads();
    }

    float* outn = out + (size_t)z * 256 * L_DIM;
    #pragma unroll
    for (int m = 0; m < 4; ++m) {
        #pragma unroll
        for (int n = 0; n < 4; ++n) {
            const int col = n0 + wc*64 + n*16 + lr;
            #pragma unroll
            for (int r = 0; r < 4; ++r) {
                const int row = m0 + wr*64 + m*16 + lk*4 + r;
                outn[(size_t)row * L_DIM + col] = acc[m][n][r] + pout_b[row];
            }
        }
    }
}

// ---------------------------------------------------------------------------
extern "C" void kernel_launch(void* const* d_in, const int* in_sizes, int n_in,
                              void* d_out, int out_size, void* d_ws, size_t ws_size,
                              hipStream_t stream) {
    const float* x      = (const float*)d_in[0];
    const float* dw_w   = (const float*)d_in[1];
    const float* dw_b   = (const float*)d_in[2];
    const float* pw_w   = (const float*)d_in[3];
    const float* pw_b   = (const float*)d_in[4];
    const float* pin_w  = (const float*)d_in[5];
    const float* pin_b  = (const float*)d_in[6];
    const float* pout_w = (const float*)d_in[7];
    const float* pout_b = (const float*)d_in[8];
    float* out = (float*)d_out;

    char* ws = (char*)d_ws;
    u16*   xb_t    = (u16*)ws;                      //  8,388,608
    u16*   dwc_t   = (u16*)(ws + 8388608);          //  8,388,608
    u16*   val_b   = (u16*)(ws + 16777216);         //  8,388,608
    u16*   acc_b   = (u16*)(ws + 25165824);         //  8,388,608
    float* omb     = (float*)(ws + 33554432);       //  7,340,032
    u16*   pin_wb  = (u16*)(ws + 40894464);         //    131,072
    u16*   pw_wb   = (u16*)(ws + 41025536);         //     65,536 (128 rows)
    u16*   pout_wb = (u16*)(ws + 41091072);         //    131,072

    // K1: depthwise conv + transpose-cast + weight casts
    prep_kernel<<<dim3(5, 64, NBATCH), 256, 0, stream>>>(
        x, dw_w, dw_b, pin_w, pw_w, pout_w,
        xb_t, dwc_t, pin_wb, pw_wb, pout_wb);

    // K2: val = pin(x) [bf16], om = pw(dwc) [fp32] — 64x128 tiles, 768 blocks
    gemm_dual<<<dim3(3, 256), 256, 0, stream>>>(
        xb_t, dwc_t, pin_wb, pw_wb, pin_b, pw_b, val_b, omb);

    // K3a: deformable gather (R15 config)
    gather_kernel<<<dim3(2048), 256, 0, stream>>>(omb, val_b, acc_b);

    // K3b: pout GEMM, transposed fp32 output
    gemm_pout<<<dim3(32, 2, NBATCH), 256, 0, stream>>>(
        acc_b, pout_wb, pout_b, out);
}